// Round 17
// baseline (105.747 us; speedup 1.0000x reference)
//
#include <hip/hip_runtime.h>
#include <hip/hip_bf16.h>
#include <math.h>
#include <stdint.h>

#define BN 2048
#define KF 512
#define OF 512
#define NH 8
#define DD 64

typedef __attribute__((ext_vector_type(8))) short short8;
typedef __attribute__((ext_vector_type(4))) float f32x4;
typedef unsigned short ushortT;

static __device__ __forceinline__ ushortT bfcvt(float f) {
  __hip_bfloat16 h = __float2bfloat16(f);
  return *reinterpret_cast<ushortT*>(&h);
}
static __device__ __forceinline__ float bf2f(ushortT b) {
  return __uint_as_float(((unsigned)b) << 16);
}

#define SPLIT8(vsrc, dhi, dlo)                                        \
  {                                                                   \
    ushortT hi8[8], lo8[8];                                           \
    _Pragma("unroll") for (int i = 0; i < 8; ++i) {                   \
      hi8[i] = bfcvt((vsrc)[i]);                                      \
      lo8[i] = bfcvt((vsrc)[i] - bf2f(hi8[i]));                       \
    }                                                                 \
    (dhi) = *(const int4*)hi8;                                        \
    (dlo) = *(const int4*)lo8;                                        \
  }

// ============ Kernel A: adj pack + split-bf16 GEMM, fragment-major h (R13) ===
__global__ __launch_bounds__(256, 2) void k_main(
    const float* __restrict__ x, const int* __restrict__ adj,
    const float* __restrict__ W, const float* __restrict__ Wb,
    const float* __restrict__ av,
    ushortT* __restrict__ hF, float* __restrict__ E12s, float* __restrict__ E12d,
    uint8_t* __restrict__ adjB) {
  __shared__ __align__(16) uint8_t smem[24576];
  __shared__ float sredS[2][32], sredD[2][32];

  const int t    = threadIdx.x;
  const int hh   = blockIdx.x;
  const int i0   = blockIdx.y * 32;
  const int b    = hh * 64 + blockIdx.y;
  const int lane = t & 63;
  const int wv   = t >> 6;
  const int mt   = wv & 1;
  const int nt   = wv >> 1;
  const int l15  = lane & 15;
  const int lq   = lane >> 4;

  {
    const int gtid = b * 256 + t;
#pragma unroll
    for (int it = 0; it < 4; ++it) {
      const int bidx = gtid + it * (512 * 256);
      const int4 v0 = *(const int4*)(adj + (size_t)bidx * 8);
      const int4 v1 = *(const int4*)(adj + (size_t)bidx * 8 + 4);
      unsigned m = (v0.x ? 1u : 0u) | (v0.y ? 2u : 0u) | (v0.z ? 4u : 0u) | (v0.w ? 8u : 0u)
                 | (v1.x ? 16u : 0u) | (v1.y ? 32u : 0u) | (v1.z ? 64u : 0u) | (v1.w ? 128u : 0u);
      adjB[bidx] = (uint8_t)m;
    }
  }

  ushortT* sAh = (ushortT*)smem;
  ushortT* sAl = sAh + 32 * 64;
  ushortT* sBh = sAl + 32 * 64;
  ushortT* sBl = sBh + 64 * 64;

  f32x4 acc[2] = {};
  const int srow = t >> 3, ss = t & 7;
  int4 aHi, aLo, bHi[2], bLo[2];

  {
    const float* xs = x + (size_t)(i0 + srow) * KF + ss * 8;
    float v[8];
    *(float4*)&v[0] = *(const float4*)xs;
    *(float4*)&v[4] = *(const float4*)(xs + 4);
    SPLIT8(v, aHi, aLo)
#pragma unroll
    for (int rp = 0; rp < 2; ++rp) {
      const int S = t + rp * 256, rw = S >> 3, s2 = S & 7;
      const float* wsrc = W + (size_t)(hh * 64 + rw) * KF + s2 * 8;
      float wv8[8];
      *(float4*)&wv8[0] = *(const float4*)wsrc;
      *(float4*)&wv8[4] = *(const float4*)(wsrc + 4);
      SPLIT8(wv8, bHi[rp], bLo[rp])
    }
  }

  for (int k0 = 0; k0 < 8; ++k0) {
    __syncthreads();
    {
      const int offA = srow * 64 + ((ss ^ (srow & 7)) * 8);
      *(int4*)&sAh[offA] = aHi;
      *(int4*)&sAl[offA] = aLo;
#pragma unroll
      for (int rp = 0; rp < 2; ++rp) {
        const int S = t + rp * 256, rw = S >> 3, s2 = S & 7;
        const int offB = rw * 64 + ((s2 ^ (rw & 7)) * 8);
        *(int4*)&sBh[offB] = bHi[rp];
        *(int4*)&sBl[offB] = bLo[rp];
      }
    }
    __syncthreads();
    if (k0 < 7) {
      const int kc = (k0 + 1) * 64;
      const float* xs = x + (size_t)(i0 + srow) * KF + kc + ss * 8;
      float v[8];
      *(float4*)&v[0] = *(const float4*)xs;
      *(float4*)&v[4] = *(const float4*)(xs + 4);
      SPLIT8(v, aHi, aLo)
#pragma unroll
      for (int rp = 0; rp < 2; ++rp) {
        const int S = t + rp * 256, rw = S >> 3, s2 = S & 7;
        const float* wsrc = W + (size_t)(hh * 64 + rw) * KF + kc + s2 * 8;
        float wv8[8];
        *(float4*)&wv8[0] = *(const float4*)wsrc;
        *(float4*)&wv8[4] = *(const float4*)(wsrc + 4);
        SPLIT8(wv8, bHi[rp], bLo[rp])
      }
    }
#pragma unroll
    for (int kb = 0; kb < 2; ++kb) {
      const int sc = kb * 4 + lq;
      const int arow = mt * 16 + l15;
      const int offA = arow * 64 + ((sc ^ (arow & 7)) * 8);
      const short8 afh = *(const short8*)&sAh[offA];
      const short8 afl = *(const short8*)&sAl[offA];
      const int br0 = nt * 32 + l15;
      const int br1 = br0 + 16;
      const int offB0 = br0 * 64 + ((sc ^ (br0 & 7)) * 8);
      const int offB1 = br1 * 64 + ((sc ^ (br1 & 7)) * 8);
      const short8 bh0 = *(const short8*)&sBh[offB0];
      const short8 bl0 = *(const short8*)&sBl[offB0];
      const short8 bh1 = *(const short8*)&sBh[offB1];
      const short8 bl1 = *(const short8*)&sBl[offB1];
      acc[0] = __builtin_amdgcn_mfma_f32_16x16x32_bf16(afh, bh0, acc[0], 0, 0, 0);
      acc[1] = __builtin_amdgcn_mfma_f32_16x16x32_bf16(afh, bh1, acc[1], 0, 0, 0);
      acc[0] = __builtin_amdgcn_mfma_f32_16x16x32_bf16(afh, bl0, acc[0], 0, 0, 0);
      acc[1] = __builtin_amdgcn_mfma_f32_16x16x32_bf16(afh, bl1, acc[1], 0, 0, 0);
      acc[0] = __builtin_amdgcn_mfma_f32_16x16x32_bf16(afl, bh0, acc[0], 0, 0, 0);
      acc[1] = __builtin_amdgcn_mfma_f32_16x16x32_bf16(afl, bh1, acc[1], 0, 0, 0);
    }
  }

  __syncthreads();
  ushortT* ldsT = (ushortT*)smem;   // [64 d][40]
  float bias2[2], asv[2], adv[2];
#pragma unroll
  for (int bb = 0; bb < 2; ++bb) {
    const int fl = nt * 32 + bb * 16 + l15;
    bias2[bb] = Wb[hh * 64 + fl];
    asv[bb] = av[fl];
    adv[bb] = av[DD + fl];
  }
#pragma unroll
  for (int p = 0; p < 4; ++p) {
    float vs = 0.f, vd = 0.f;
#pragma unroll
    for (int bb = 0; bb < 2; ++bb) {
      const float hv = acc[bb][p] + bias2[bb];
      const ushortT hu = bfcvt(hv);
      vs = fmaf(hv, asv[bb], vs);
      vd = fmaf(hv, adv[bb], vd);
      ldsT[(nt * 32 + bb * 16 + l15) * 40 + mt * 16 + lq * 4 + p] = hu;
    }
    vs += __shfl_xor(vs, 1); vs += __shfl_xor(vs, 2);
    vs += __shfl_xor(vs, 4); vs += __shfl_xor(vs, 8);
    vd += __shfl_xor(vd, 1); vd += __shfl_xor(vd, 2);
    vd += __shfl_xor(vd, 4); vd += __shfl_xor(vd, 8);
    if (l15 == 0) {
      sredS[nt][mt * 16 + lq * 4 + p] = vs;
      sredD[nt][mt * 16 + lq * 4 + p] = vd;
    }
  }
  __syncthreads();
  if (t < 32) {
    const float s1 = sredS[0][t] + sredS[1][t];
    const float s2 = sredD[0][t] + sredD[1][t];
    const size_t gi = (size_t)hh * BN + i0 + t;
    float2 sv; sv.x = __expf(s1); sv.y = __expf(0.2f * s1);
    float2 dv; dv.x = __expf(s2); dv.y = __expf(0.2f * s2);
    *(float2*)&E12s[gi * 2] = sv;
    *(float2*)&E12d[gi * 2] = dv;
  }
  {
    const int n = t >> 6, ln = t & 63;
    const int4 v = *(const int4*)&ldsT[(n * 16 + (ln & 15)) * 40 + ((ln >> 4) * 8)];
    const size_t chunk = (((size_t)hh * 64 + blockIdx.y) * 4 + n) * 64 + ln;
    *(int4*)&hF[chunk * 8] = v;
  }
}

// ============ Kernel B v5: v3 + LDS phase-overlay -> 4 blocks/CU (8 w/SIMD) ==
// Phase 1 (main loop): arena = e12[16KB] + abits[8.5KB].
// Phase 2 (combine):  arena = cbuf[34.8KB].  One barrier separates phases.
__global__ __launch_bounds__(512, 8) void k_attn(
    const ushortT* __restrict__ hF, const uint8_t* __restrict__ adjB,
    const float* __restrict__ E12s, const float* __restrict__ E12d,
    float* __restrict__ out) {
  __shared__ __align__(16) uint8_t arena[34816];   // overlay
  __shared__ float denP[8][2][16];                 // 1 KB

  float* e12 = (float*)arena;                      // 16384 B
  uint8_t* abits = arena + 16384;                  // 8704 B
  float* cbuf = (float*)arena;                     // 34816 B (phase 2)

  const int t    = threadIdx.x;
  const int hh   = blockIdx.x;
  const int i0   = blockIdx.y * 32;
  const int lane = t & 63;
  const int wv   = t >> 6;
  const int l15  = lane & 15;
  const int lq   = lane >> 4;

  {
    const float4* g = (const float4*)(E12d + (size_t)hh * BN * 2);
    ((float4*)e12)[t]       = g[t];
    ((float4*)e12)[t + 512] = g[t + 512];
    const int r = t >> 4, pp = t & 15;
    *(int4*)(abits + r * 272 + pp * 16) =
        *(const int4*)(adjB + (size_t)(i0 + r) * 256 + pp * 16);
  }

  const float2 eiA = *(const float2*)&E12s[2 * ((size_t)hh * BN + i0 + l15)];
  const float2 eiB = *(const float2*)&E12s[2 * ((size_t)hh * BN + i0 + 16 + l15)];

  const short8 ones8 = {(short)0x3F80, (short)0x3F80, (short)0x3F80, (short)0x3F80,
                        (short)0x3F80, (short)0x3F80, (short)0x3F80, (short)0x3F80};

  const ushortT* hfb = hF + (size_t)hh * 131072 + (size_t)lane * 8;

  __syncthreads();   // e12 + abits staged

  const uint4 wA0 = *(const uint4*)(abits + l15 * 272 + wv * 32);
  const uint4 wA1 = *(const uint4*)(abits + l15 * 272 + wv * 32 + 16);
  const uint4 wB0 = *(const uint4*)(abits + (16 + l15) * 272 + wv * 32);
  const uint4 wB1 = *(const uint4*)(abits + (16 + l15) * 272 + wv * 32 + 16);
  const int lqs = lq * 8;

  f32x4 acc0[4] = {}, acc1[4] = {};
  f32x4 accd0 = {0.f, 0.f, 0.f, 0.f}, accd1 = {0.f, 0.f, 0.f, 0.f};

  const int jb0 = wv * 8;
  short8 bfA[4], bfB[4];
  {
    const ushortT* b0 = hfb + (size_t)(jb0 * 4) * 512;
#pragma unroll
    for (int n = 0; n < 4; ++n) bfA[n] = *(const short8*)(b0 + (size_t)n * 512);
  }

#define WSEL0(s) ((s)==0?wA0.x:(s)==1?wA0.y:(s)==2?wA0.z:(s)==3?wA0.w: \
                  (s)==4?wA1.x:(s)==5?wA1.y:(s)==6?wA1.z:wA1.w)
#define WSEL1(s) ((s)==0?wB0.x:(s)==1?wB0.y:(s)==2?wB0.z:(s)==3?wB0.w: \
                  (s)==4?wB1.x:(s)==5?wB1.y:(s)==6?wB1.z:wB1.w)

#define STEP(s, BCUR, BNXT)                                                        \
  {                                                                                \
    if ((s) < 7) {                                                                 \
      const ushortT* bn = hfb + (size_t)((jb0 + (s) + 1) * 4) * 512;               \
      _Pragma("unroll") for (int n = 0; n < 4; ++n)                                \
        BNXT[n] = *(const short8*)(bn + (size_t)n * 512);                          \
    }                                                                              \
    const int j0 = (jb0 + (s)) * 32 + lq * 8;                                      \
    const float* ep = &e12[j0 * 2];                                                \
    const float4 r0 = *(const float4*)(ep);                                        \
    const float4 r1 = *(const float4*)(ep + 4);                                    \
    const float4 r2 = *(const float4*)(ep + 8);                                    \
    const float4 r3 = *(const float4*)(ep + 12);                                   \
    const unsigned bb0 = (WSEL0(s) >> lqs) & 0xffu;                                \
    const unsigned bb1 = (WSEL1(s) >> lqs) & 0xffu;                                \
    unsigned pk0[4], pk1[4];                                                       \
    _Pragma("unroll") for (int q = 0; q < 4; ++q) {                                \
      const float4 rq = (q == 0) ? r0 : (q == 1) ? r1 : (q == 2) ? r2 : r3;        \
      float wa0 = fmaxf(eiA.x * rq.x, eiA.y * rq.y);                               \
      float wb0 = fmaxf(eiA.x * rq.z, eiA.y * rq.w);                               \
      float wa1 = fmaxf(eiB.x * rq.x, eiB.y * rq.y);                               \
      float wb1 = fmaxf(eiB.x * rq.z, eiB.y * rq.w);                               \
      wa0 = ((bb0 >> (2 * q)) & 1u) ? wa0 : 0.f;                                   \
      wb0 = ((bb0 >> (2 * q + 1)) & 1u) ? wb0 : 0.f;                               \
      wa1 = ((bb1 >> (2 * q)) & 1u) ? wa1 : 0.f;                                   \
      wb1 = ((bb1 >> (2 * q + 1)) & 1u) ? wb1 : 0.f;                               \
      asm("v_cvt_pk_bf16_f32 %0, %1, %2" : "=v"(pk0[q]) : "v"(wa0), "v"(wb0));     \
      asm("v_cvt_pk_bf16_f32 %0, %1, %2" : "=v"(pk1[q]) : "v"(wa1), "v"(wb1));     \
    }                                                                              \
    const short8 af0 = *(const short8*)pk0;                                        \
    const short8 af1 = *(const short8*)pk1;                                        \
    _Pragma("unroll") for (int n = 0; n < 4; ++n) {                                \
      acc0[n] = __builtin_amdgcn_mfma_f32_16x16x32_bf16(af0, BCUR[n], acc0[n], 0, 0, 0); \
      acc1[n] = __builtin_amdgcn_mfma_f32_16x16x32_bf16(af1, BCUR[n], acc1[n], 0, 0, 0); \
    }                                                                              \
    accd0 = __builtin_amdgcn_mfma_f32_16x16x32_bf16(af0, ones8, accd0, 0, 0, 0);   \
    accd1 = __builtin_amdgcn_mfma_f32_16x16x32_bf16(af1, ones8, accd1, 0, 0, 0);   \
  }

  STEP(0, bfA, bfB) STEP(1, bfB, bfA) STEP(2, bfA, bfB) STEP(3, bfB, bfA)
  STEP(4, bfA, bfB) STEP(5, bfB, bfA) STEP(6, bfA, bfB) STEP(7, bfB, bfA)
#undef STEP
#undef WSEL0
#undef WSEL1

  if (l15 == 0) {
#pragma unroll
    for (int p = 0; p < 4; ++p) {
      denP[wv][0][lq * 4 + p] = accd0[p];
      denP[wv][1][lq * 4 + p] = accd1[p];
    }
  }

  __syncthreads();   // PHASE BOUNDARY: all e12/abits reads done; arena -> cbuf

#define CWRITE(buf)                                                     \
  _Pragma("unroll") for (int n = 0; n < 4; ++n)                         \
  _Pragma("unroll") for (int p = 0; p < 4; ++p) {                       \
    (buf)[(lq * 4 + p) * 68 + n * 16 + l15]      = acc0[n][p];          \
    (buf)[(16 + lq * 4 + p) * 68 + n * 16 + l15] = acc1[n][p];          \
  }
#define CADD(buf)                                                       \
  _Pragma("unroll") for (int n = 0; n < 4; ++n)                         \
  _Pragma("unroll") for (int p = 0; p < 4; ++p) {                       \
    acc0[n][p] += (buf)[(lq * 4 + p) * 68 + n * 16 + l15];              \
    acc1[n][p] += (buf)[(16 + lq * 4 + p) * 68 + n * 16 + l15];         \
  }

  if (wv >= 4) { CWRITE((cbuf + (wv - 4) * 2176)) }
  __syncthreads();
  if (wv < 4) {
    CADD((cbuf + wv * 2176))
    if (wv >= 2) { CWRITE((cbuf + wv * 2176)) }
  }
  __syncthreads();
  if (wv < 2) {
    CADD((cbuf + (wv + 2) * 2176))
    if (wv == 1) { CWRITE((cbuf + 2176)) }
  }
  __syncthreads();
  if (wv == 0) {
    CADD((cbuf + 2176))
    float dfin0[4], dfin1[4];
#pragma unroll
    for (int p = 0; p < 4; ++p) {
      const int row = lq * 4 + p;
      float d0 = 0.f, d1s = 0.f;
#pragma unroll
      for (int w = 0; w < 8; ++w) { d0 += denP[w][0][row]; d1s += denP[w][1][row]; }
      dfin0[p] = 1.f / d0;
      dfin1[p] = 1.f / d1s;
    }
#pragma unroll
    for (int n = 0; n < 4; ++n)
#pragma unroll
      for (int p = 0; p < 4; ++p) {
        float v0 = acc0[n][p] * dfin0[p];
        float v1 = acc1[n][p] * dfin1[p];
        v0 = v0 > 0.f ? v0 : expm1f(v0);
        v1 = v1 > 0.f ? v1 : expm1f(v1);
        out[(size_t)(i0 + lq * 4 + p) * OF + hh * 64 + n * 16 + l15] = v0;
        out[(size_t)(i0 + 16 + lq * 4 + p) * OF + hh * 64 + n * 16 + l15] = v1;
      }
  }
#undef CWRITE
#undef CADD
}

extern "C" void kernel_launch(void* const* d_in, const int* in_sizes, int n_in,
                              void* d_out, int out_size, void* d_ws, size_t ws_size,
                              hipStream_t stream) {
  const float* x  = (const float*)d_in[0];
  const int* adj  = (const int*)d_in[1];
  const float* Ww = (const float*)d_in[2];
  const float* Wb = (const float*)d_in[3];
  const float* a  = (const float*)d_in[4];
  float* outp = (float*)d_out;

  uint8_t* p = (uint8_t*)d_ws;
  ushortT* hF   = (ushortT*)(p + 0x000000);   // 2 MB, fragment-major
  float*   E12d = (float*)  (p + 0x200000);   // 128 KB
  float*   E12s = (float*)  (p + 0x220000);   // 128 KB
  uint8_t* adjB =            p + 0x240000;    // 512 KB

  k_main<<<dim3(NH, BN / 32), 256, 0, stream>>>(x, adj, Ww, Wb, a, hF, E12s, E12d, adjB);
  k_attn<<<dim3(NH, BN / 32), 512, 0, stream>>>(hF, adjB, E12s, E12d, outp);
}

// Round 18
// 36.494 us; speedup vs baseline: 2.8976x; 2.8976x over previous
//
#include <hip/hip_runtime.h>
#include <hip/hip_bf16.h>
#include <math.h>
#include <stdint.h>

#define BN 2048
#define KF 512
#define OF 512
#define NH 8
#define DD 64

typedef __attribute__((ext_vector_type(8))) short short8;
typedef __attribute__((ext_vector_type(4))) float f32x4;
typedef unsigned short ushortT;

static __device__ __forceinline__ ushortT bfcvt(float f) {
  __hip_bfloat16 h = __float2bfloat16(f);
  return *reinterpret_cast<ushortT*>(&h);
}
static __device__ __forceinline__ float bf2f(ushortT b) {
  return __uint_as_float(((unsigned)b) << 16);
}

#define SPLIT8(vsrc, dhi, dlo)                                        \
  {                                                                   \
    ushortT hi8[8], lo8[8];                                           \
    _Pragma("unroll") for (int i = 0; i < 8; ++i) {                   \
      hi8[i] = bfcvt((vsrc)[i]);                                      \
      lo8[i] = bfcvt((vsrc)[i] - bf2f(hi8[i]));                       \
    }                                                                 \
    (dhi) = *(const int4*)hi8;                                        \
    (dlo) = *(const int4*)lo8;                                        \
  }

// ============ Kernel A: adj pack + split-bf16 GEMM, fragment-major h (R13) ===
__global__ __launch_bounds__(256, 2) void k_main(
    const float* __restrict__ x, const int* __restrict__ adj,
    const float* __restrict__ W, const float* __restrict__ Wb,
    const float* __restrict__ av,
    ushortT* __restrict__ hF, float* __restrict__ E12s, float* __restrict__ E12d,
    uint8_t* __restrict__ adjB) {
  __shared__ __align__(16) uint8_t smem[24576];
  __shared__ float sredS[2][32], sredD[2][32];

  const int t    = threadIdx.x;
  const int hh   = blockIdx.x;
  const int i0   = blockIdx.y * 32;
  const int b    = hh * 64 + blockIdx.y;
  const int lane = t & 63;
  const int wv   = t >> 6;
  const int mt   = wv & 1;
  const int nt   = wv >> 1;
  const int l15  = lane & 15;
  const int lq   = lane >> 4;

  {
    const int gtid = b * 256 + t;
#pragma unroll
    for (int it = 0; it < 4; ++it) {
      const int bidx = gtid + it * (512 * 256);
      const int4 v0 = *(const int4*)(adj + (size_t)bidx * 8);
      const int4 v1 = *(const int4*)(adj + (size_t)bidx * 8 + 4);
      unsigned m = (v0.x ? 1u : 0u) | (v0.y ? 2u : 0u) | (v0.z ? 4u : 0u) | (v0.w ? 8u : 0u)
                 | (v1.x ? 16u : 0u) | (v1.y ? 32u : 0u) | (v1.z ? 64u : 0u) | (v1.w ? 128u : 0u);
      adjB[bidx] = (uint8_t)m;
    }
  }

  ushortT* sAh = (ushortT*)smem;
  ushortT* sAl = sAh + 32 * 64;
  ushortT* sBh = sAl + 32 * 64;
  ushortT* sBl = sBh + 64 * 64;

  f32x4 acc[2] = {};
  const int srow = t >> 3, ss = t & 7;
  int4 aHi, aLo, bHi[2], bLo[2];

  {
    const float* xs = x + (size_t)(i0 + srow) * KF + ss * 8;
    float v[8];
    *(float4*)&v[0] = *(const float4*)xs;
    *(float4*)&v[4] = *(const float4*)(xs + 4);
    SPLIT8(v, aHi, aLo)
#pragma unroll
    for (int rp = 0; rp < 2; ++rp) {
      const int S = t + rp * 256, rw = S >> 3, s2 = S & 7;
      const float* wsrc = W + (size_t)(hh * 64 + rw) * KF + s2 * 8;
      float wv8[8];
      *(float4*)&wv8[0] = *(const float4*)wsrc;
      *(float4*)&wv8[4] = *(const float4*)(wsrc + 4);
      SPLIT8(wv8, bHi[rp], bLo[rp])
    }
  }

  for (int k0 = 0; k0 < 8; ++k0) {
    __syncthreads();
    {
      const int offA = srow * 64 + ((ss ^ (srow & 7)) * 8);
      *(int4*)&sAh[offA] = aHi;
      *(int4*)&sAl[offA] = aLo;
#pragma unroll
      for (int rp = 0; rp < 2; ++rp) {
        const int S = t + rp * 256, rw = S >> 3, s2 = S & 7;
        const int offB = rw * 64 + ((s2 ^ (rw & 7)) * 8);
        *(int4*)&sBh[offB] = bHi[rp];
        *(int4*)&sBl[offB] = bLo[rp];
      }
    }
    __syncthreads();
    if (k0 < 7) {
      const int kc = (k0 + 1) * 64;
      const float* xs = x + (size_t)(i0 + srow) * KF + kc + ss * 8;
      float v[8];
      *(float4*)&v[0] = *(const float4*)xs;
      *(float4*)&v[4] = *(const float4*)(xs + 4);
      SPLIT8(v, aHi, aLo)
#pragma unroll
      for (int rp = 0; rp < 2; ++rp) {
        const int S = t + rp * 256, rw = S >> 3, s2 = S & 7;
        const float* wsrc = W + (size_t)(hh * 64 + rw) * KF + kc + s2 * 8;
        float wv8[8];
        *(float4*)&wv8[0] = *(const float4*)wsrc;
        *(float4*)&wv8[4] = *(const float4*)(wsrc + 4);
        SPLIT8(wv8, bHi[rp], bLo[rp])
      }
    }
#pragma unroll
    for (int kb = 0; kb < 2; ++kb) {
      const int sc = kb * 4 + lq;
      const int arow = mt * 16 + l15;
      const int offA = arow * 64 + ((sc ^ (arow & 7)) * 8);
      const short8 afh = *(const short8*)&sAh[offA];
      const short8 afl = *(const short8*)&sAl[offA];
      const int br0 = nt * 32 + l15;
      const int br1 = br0 + 16;
      const int offB0 = br0 * 64 + ((sc ^ (br0 & 7)) * 8);
      const int offB1 = br1 * 64 + ((sc ^ (br1 & 7)) * 8);
      const short8 bh0 = *(const short8*)&sBh[offB0];
      const short8 bl0 = *(const short8*)&sBl[offB0];
      const short8 bh1 = *(const short8*)&sBh[offB1];
      const short8 bl1 = *(const short8*)&sBl[offB1];
      acc[0] = __builtin_amdgcn_mfma_f32_16x16x32_bf16(afh, bh0, acc[0], 0, 0, 0);
      acc[1] = __builtin_amdgcn_mfma_f32_16x16x32_bf16(afh, bh1, acc[1], 0, 0, 0);
      acc[0] = __builtin_amdgcn_mfma_f32_16x16x32_bf16(afh, bl0, acc[0], 0, 0, 0);
      acc[1] = __builtin_amdgcn_mfma_f32_16x16x32_bf16(afh, bl1, acc[1], 0, 0, 0);
      acc[0] = __builtin_amdgcn_mfma_f32_16x16x32_bf16(afl, bh0, acc[0], 0, 0, 0);
      acc[1] = __builtin_amdgcn_mfma_f32_16x16x32_bf16(afl, bh1, acc[1], 0, 0, 0);
    }
  }

  __syncthreads();
  ushortT* ldsT = (ushortT*)smem;   // [64 d][40]
  float bias2[2], asv[2], adv[2];
#pragma unroll
  for (int bb = 0; bb < 2; ++bb) {
    const int fl = nt * 32 + bb * 16 + l15;
    bias2[bb] = Wb[hh * 64 + fl];
    asv[bb] = av[fl];
    adv[bb] = av[DD + fl];
  }
#pragma unroll
  for (int p = 0; p < 4; ++p) {
    float vs = 0.f, vd = 0.f;
#pragma unroll
    for (int bb = 0; bb < 2; ++bb) {
      const float hv = acc[bb][p] + bias2[bb];
      const ushortT hu = bfcvt(hv);
      vs = fmaf(hv, asv[bb], vs);
      vd = fmaf(hv, adv[bb], vd);
      ldsT[(nt * 32 + bb * 16 + l15) * 40 + mt * 16 + lq * 4 + p] = hu;
    }
    vs += __shfl_xor(vs, 1); vs += __shfl_xor(vs, 2);
    vs += __shfl_xor(vs, 4); vs += __shfl_xor(vs, 8);
    vd += __shfl_xor(vd, 1); vd += __shfl_xor(vd, 2);
    vd += __shfl_xor(vd, 4); vd += __shfl_xor(vd, 8);
    if (l15 == 0) {
      sredS[nt][mt * 16 + lq * 4 + p] = vs;
      sredD[nt][mt * 16 + lq * 4 + p] = vd;
    }
  }
  __syncthreads();
  if (t < 32) {
    const float s1 = sredS[0][t] + sredS[1][t];
    const float s2 = sredD[0][t] + sredD[1][t];
    const size_t gi = (size_t)hh * BN + i0 + t;
    float2 sv; sv.x = __expf(s1); sv.y = __expf(0.2f * s1);
    float2 dv; dv.x = __expf(s2); dv.y = __expf(0.2f * s2);
    *(float2*)&E12s[gi * 2] = sv;
    *(float2*)&E12d[gi * 2] = dv;
  }
  {
    const int n = t >> 6, ln = t & 63;
    const int4 v = *(const int4*)&ldsT[(n * 16 + (ln & 15)) * 40 + ((ln >> 4) * 8)];
    const size_t chunk = (((size_t)hh * 64 + blockIdx.y) * 4 + n) * 64 + ln;
    *(int4*)&hF[chunk * 8] = v;
  }
}

// ============ Kernel B v6: overlay LDS (35KB) + UNCAPPED regs (bounds 512,4) =
// Compiler chose 64 VGPR at this bound in R15; with 35KB LDS that yields
// 4 blocks/CU (8 waves/SIMD) at runtime without forcing the allocator.
__global__ __launch_bounds__(512, 4) void k_attn(
    const ushortT* __restrict__ hF, const uint8_t* __restrict__ adjB,
    const float* __restrict__ E12s, const float* __restrict__ E12d,
    float* __restrict__ out) {
  __shared__ __align__(16) uint8_t arena[34816];   // overlay
  __shared__ float denP[8][2][16];                 // 1 KB

  float* e12 = (float*)arena;                      // 16384 B (phase 1)
  uint8_t* abits = arena + 16384;                  // 8704 B  (phase 1)
  float* cbuf = (float*)arena;                     // 34816 B (phase 2)

  const int t    = threadIdx.x;
  const int hh   = blockIdx.x;
  const int i0   = blockIdx.y * 32;
  const int lane = t & 63;
  const int wv   = t >> 6;
  const int l15  = lane & 15;
  const int lq   = lane >> 4;

  {
    const float4* g = (const float4*)(E12d + (size_t)hh * BN * 2);
    ((float4*)e12)[t]       = g[t];
    ((float4*)e12)[t + 512] = g[t + 512];
    const int r = t >> 4, pp = t & 15;
    *(int4*)(abits + r * 272 + pp * 16) =
        *(const int4*)(adjB + (size_t)(i0 + r) * 256 + pp * 16);
  }

  const float2 eiA = *(const float2*)&E12s[2 * ((size_t)hh * BN + i0 + l15)];
  const float2 eiB = *(const float2*)&E12s[2 * ((size_t)hh * BN + i0 + 16 + l15)];

  const short8 ones8 = {(short)0x3F80, (short)0x3F80, (short)0x3F80, (short)0x3F80,
                        (short)0x3F80, (short)0x3F80, (short)0x3F80, (short)0x3F80};

  const ushortT* hfb = hF + (size_t)hh * 131072 + (size_t)lane * 8;

  __syncthreads();   // e12 + abits staged

  const uint4 wA0 = *(const uint4*)(abits + l15 * 272 + wv * 32);
  const uint4 wA1 = *(const uint4*)(abits + l15 * 272 + wv * 32 + 16);
  const uint4 wB0 = *(const uint4*)(abits + (16 + l15) * 272 + wv * 32);
  const uint4 wB1 = *(const uint4*)(abits + (16 + l15) * 272 + wv * 32 + 16);
  const int lqs = lq * 8;

  f32x4 acc0[4] = {}, acc1[4] = {};
  f32x4 accd0 = {0.f, 0.f, 0.f, 0.f}, accd1 = {0.f, 0.f, 0.f, 0.f};

  const int jb0 = wv * 8;
  short8 bfA[4], bfB[4];
  {
    const ushortT* b0 = hfb + (size_t)(jb0 * 4) * 512;
#pragma unroll
    for (int n = 0; n < 4; ++n) bfA[n] = *(const short8*)(b0 + (size_t)n * 512);
  }

#define WSEL0(s) ((s)==0?wA0.x:(s)==1?wA0.y:(s)==2?wA0.z:(s)==3?wA0.w: \
                  (s)==4?wA1.x:(s)==5?wA1.y:(s)==6?wA1.z:wA1.w)
#define WSEL1(s) ((s)==0?wB0.x:(s)==1?wB0.y:(s)==2?wB0.z:(s)==3?wB0.w: \
                  (s)==4?wB1.x:(s)==5?wB1.y:(s)==6?wB1.z:wB1.w)

#define STEP(s, BCUR, BNXT)                                                        \
  {                                                                                \
    if ((s) < 7) {                                                                 \
      const ushortT* bn = hfb + (size_t)((jb0 + (s) + 1) * 4) * 512;               \
      _Pragma("unroll") for (int n = 0; n < 4; ++n)                                \
        BNXT[n] = *(const short8*)(bn + (size_t)n * 512);                          \
    }                                                                              \
    const int j0 = (jb0 + (s)) * 32 + lq * 8;                                      \
    const float* ep = &e12[j0 * 2];                                                \
    const float4 r0 = *(const float4*)(ep);                                        \
    const float4 r1 = *(const float4*)(ep + 4);                                    \
    const float4 r2 = *(const float4*)(ep + 8);                                    \
    const float4 r3 = *(const float4*)(ep + 12);                                   \
    const unsigned bb0 = (WSEL0(s) >> lqs) & 0xffu;                                \
    const unsigned bb1 = (WSEL1(s) >> lqs) & 0xffu;                                \
    unsigned pk0[4], pk1[4];                                                       \
    _Pragma("unroll") for (int q = 0; q < 4; ++q) {                                \
      const float4 rq = (q == 0) ? r0 : (q == 1) ? r1 : (q == 2) ? r2 : r3;        \
      float wa0 = fmaxf(eiA.x * rq.x, eiA.y * rq.y);                               \
      float wb0 = fmaxf(eiA.x * rq.z, eiA.y * rq.w);                               \
      float wa1 = fmaxf(eiB.x * rq.x, eiB.y * rq.y);                               \
      float wb1 = fmaxf(eiB.x * rq.z, eiB.y * rq.w);                               \
      wa0 = ((bb0 >> (2 * q)) & 1u) ? wa0 : 0.f;                                   \
      wb0 = ((bb0 >> (2 * q + 1)) & 1u) ? wb0 : 0.f;                               \
      wa1 = ((bb1 >> (2 * q)) & 1u) ? wa1 : 0.f;                                   \
      wb1 = ((bb1 >> (2 * q + 1)) & 1u) ? wb1 : 0.f;                               \
      asm("v_cvt_pk_bf16_f32 %0, %1, %2" : "=v"(pk0[q]) : "v"(wa0), "v"(wb0));     \
      asm("v_cvt_pk_bf16_f32 %0, %1, %2" : "=v"(pk1[q]) : "v"(wa1), "v"(wb1));     \
    }                                                                              \
    const short8 af0 = *(const short8*)pk0;                                        \
    const short8 af1 = *(const short8*)pk1;                                        \
    _Pragma("unroll") for (int n = 0; n < 4; ++n) {                                \
      acc0[n] = __builtin_amdgcn_mfma_f32_16x16x32_bf16(af0, BCUR[n], acc0[n], 0, 0, 0); \
      acc1[n] = __builtin_amdgcn_mfma_f32_16x16x32_bf16(af1, BCUR[n], acc1[n], 0, 0, 0); \
    }                                                                              \
    accd0 = __builtin_amdgcn_mfma_f32_16x16x32_bf16(af0, ones8, accd0, 0, 0, 0);   \
    accd1 = __builtin_amdgcn_mfma_f32_16x16x32_bf16(af1, ones8, accd1, 0, 0, 0);   \
  }

  STEP(0, bfA, bfB) STEP(1, bfB, bfA) STEP(2, bfA, bfB) STEP(3, bfB, bfA)
  STEP(4, bfA, bfB) STEP(5, bfB, bfA) STEP(6, bfA, bfB) STEP(7, bfB, bfA)
#undef STEP
#undef WSEL0
#undef WSEL1

  if (l15 == 0) {
#pragma unroll
    for (int p = 0; p < 4; ++p) {
      denP[wv][0][lq * 4 + p] = accd0[p];
      denP[wv][1][lq * 4 + p] = accd1[p];
    }
  }

  __syncthreads();   // PHASE BOUNDARY: all e12/abits reads done; arena -> cbuf

#define CWRITE(buf)                                                     \
  _Pragma("unroll") for (int n = 0; n < 4; ++n)                         \
  _Pragma("unroll") for (int p = 0; p < 4; ++p) {                       \
    (buf)[(lq * 4 + p) * 68 + n * 16 + l15]      = acc0[n][p];          \
    (buf)[(16 + lq * 4 + p) * 68 + n * 16 + l15] = acc1[n][p];          \
  }
#define CADD(buf)                                                       \
  _Pragma("unroll") for (int n = 0; n < 4; ++n)                         \
  _Pragma("unroll") for (int p = 0; p < 4; ++p) {                       \
    acc0[n][p] += (buf)[(lq * 4 + p) * 68 + n * 16 + l15];              \
    acc1[n][p] += (buf)[(16 + lq * 4 + p) * 68 + n * 16 + l15];         \
  }

  if (wv >= 4) { CWRITE((cbuf + (wv - 4) * 2176)) }
  __syncthreads();
  if (wv < 4) {
    CADD((cbuf + wv * 2176))
    if (wv >= 2) { CWRITE((cbuf + wv * 2176)) }
  }
  __syncthreads();
  if (wv < 2) {
    CADD((cbuf + (wv + 2) * 2176))
    if (wv == 1) { CWRITE((cbuf + 2176)) }
  }
  __syncthreads();
  if (wv == 0) {
    CADD((cbuf + 2176))
    float dfin0[4], dfin1[4];
#pragma unroll
    for (int p = 0; p < 4; ++p) {
      const int row = lq * 4 + p;
      float d0 = 0.f, d1s = 0.f;
#pragma unroll
      for (int w = 0; w < 8; ++w) { d0 += denP[w][0][row]; d1s += denP[w][1][row]; }
      dfin0[p] = 1.f / d0;
      dfin1[p] = 1.f / d1s;
    }
#pragma unroll
    for (int n = 0; n < 4; ++n)
#pragma unroll
      for (int p = 0; p < 4; ++p) {
        float v0 = acc0[n][p] * dfin0[p];
        float v1 = acc1[n][p] * dfin1[p];
        v0 = v0 > 0.f ? v0 : expm1f(v0);
        v1 = v1 > 0.f ? v1 : expm1f(v1);
        out[(size_t)(i0 + lq * 4 + p) * OF + hh * 64 + n * 16 + l15] = v0;
        out[(size_t)(i0 + 16 + lq * 4 + p) * OF + hh * 64 + n * 16 + l15] = v1;
      }
  }
#undef CWRITE
#undef CADD
}

extern "C" void kernel_launch(void* const* d_in, const int* in_sizes, int n_in,
                              void* d_out, int out_size, void* d_ws, size_t ws_size,
                              hipStream_t stream) {
  const float* x  = (const float*)d_in[0];
  const int* adj  = (const int*)d_in[1];
  const float* Ww = (const float*)d_in[2];
  const float* Wb = (const float*)d_in[3];
  const float* a  = (const float*)d_in[4];
  float* outp = (float*)d_out;

  uint8_t* p = (uint8_t*)d_ws;
  ushortT* hF   = (ushortT*)(p + 0x000000);   // 2 MB, fragment-major
  float*   E12d = (float*)  (p + 0x200000);   // 128 KB
  float*   E12s = (float*)  (p + 0x220000);   // 128 KB
  uint8_t* adjB =            p + 0x240000;    // 512 KB

  k_main<<<dim3(NH, BN / 32), 256, 0, stream>>>(x, adj, Ww, Wb, a, hF, E12s, E12d, adjB);
  k_attn<<<dim3(NH, BN / 32), 512, 0, stream>>>(hF, adjB, E12s, E12d, outp);
}

// Round 19
// 33.078 us; speedup vs baseline: 3.1969x; 1.1033x over previous
//
#include <hip/hip_runtime.h>
#include <hip/hip_bf16.h>
#include <math.h>
#include <stdint.h>

#define BN 2048
#define KF 512
#define OF 512
#define NH 8
#define DD 64

typedef __attribute__((ext_vector_type(8))) short short8;
typedef __attribute__((ext_vector_type(4))) float f32x4;
typedef unsigned short ushortT;

static __device__ __forceinline__ ushortT bfcvt(float f) {
  __hip_bfloat16 h = __float2bfloat16(f);
  return *reinterpret_cast<ushortT*>(&h);
}
static __device__ __forceinline__ float bf2f(ushortT b) {
  return __uint_as_float(((unsigned)b) << 16);
}

#define SPLIT8(vsrc, dhi, dlo)                                        \
  {                                                                   \
    ushortT hi8[8], lo8[8];                                           \
    _Pragma("unroll") for (int i = 0; i < 8; ++i) {                   \
      hi8[i] = bfcvt((vsrc)[i]);                                      \
      lo8[i] = bfcvt((vsrc)[i] - bf2f(hi8[i]));                       \
    }                                                                 \
    (dhi) = *(const int4*)hi8;                                        \
    (dlo) = *(const int4*)lo8;                                        \
  }

// ============ Kernel A: adj pack + split-bf16 GEMM, fragment-major h (R13) ===
__global__ __launch_bounds__(256, 2) void k_main(
    const float* __restrict__ x, const int* __restrict__ adj,
    const float* __restrict__ W, const float* __restrict__ Wb,
    const float* __restrict__ av,
    ushortT* __restrict__ hF, float* __restrict__ E12s, float* __restrict__ E12d,
    uint8_t* __restrict__ adjB) {
  __shared__ __align__(16) uint8_t smem[24576];
  __shared__ float sredS[2][32], sredD[2][32];

  const int t    = threadIdx.x;
  const int hh   = blockIdx.x;
  const int i0   = blockIdx.y * 32;
  const int b    = hh * 64 + blockIdx.y;
  const int lane = t & 63;
  const int wv   = t >> 6;
  const int mt   = wv & 1;
  const int nt   = wv >> 1;
  const int l15  = lane & 15;
  const int lq   = lane >> 4;

  {
    const int gtid = b * 256 + t;
#pragma unroll
    for (int it = 0; it < 4; ++it) {
      const int bidx = gtid + it * (512 * 256);
      const int4 v0 = *(const int4*)(adj + (size_t)bidx * 8);
      const int4 v1 = *(const int4*)(adj + (size_t)bidx * 8 + 4);
      unsigned m = (v0.x ? 1u : 0u) | (v0.y ? 2u : 0u) | (v0.z ? 4u : 0u) | (v0.w ? 8u : 0u)
                 | (v1.x ? 16u : 0u) | (v1.y ? 32u : 0u) | (v1.z ? 64u : 0u) | (v1.w ? 128u : 0u);
      adjB[bidx] = (uint8_t)m;
    }
  }

  ushortT* sAh = (ushortT*)smem;
  ushortT* sAl = sAh + 32 * 64;
  ushortT* sBh = sAl + 32 * 64;
  ushortT* sBl = sBh + 64 * 64;

  f32x4 acc[2] = {};
  const int srow = t >> 3, ss = t & 7;
  int4 aHi, aLo, bHi[2], bLo[2];

  {
    const float* xs = x + (size_t)(i0 + srow) * KF + ss * 8;
    float v[8];
    *(float4*)&v[0] = *(const float4*)xs;
    *(float4*)&v[4] = *(const float4*)(xs + 4);
    SPLIT8(v, aHi, aLo)
#pragma unroll
    for (int rp = 0; rp < 2; ++rp) {
      const int S = t + rp * 256, rw = S >> 3, s2 = S & 7;
      const float* wsrc = W + (size_t)(hh * 64 + rw) * KF + s2 * 8;
      float wv8[8];
      *(float4*)&wv8[0] = *(const float4*)wsrc;
      *(float4*)&wv8[4] = *(const float4*)(wsrc + 4);
      SPLIT8(wv8, bHi[rp], bLo[rp])
    }
  }

  for (int k0 = 0; k0 < 8; ++k0) {
    __syncthreads();
    {
      const int offA = srow * 64 + ((ss ^ (srow & 7)) * 8);
      *(int4*)&sAh[offA] = aHi;
      *(int4*)&sAl[offA] = aLo;
#pragma unroll
      for (int rp = 0; rp < 2; ++rp) {
        const int S = t + rp * 256, rw = S >> 3, s2 = S & 7;
        const int offB = rw * 64 + ((s2 ^ (rw & 7)) * 8);
        *(int4*)&sBh[offB] = bHi[rp];
        *(int4*)&sBl[offB] = bLo[rp];
      }
    }
    __syncthreads();
    if (k0 < 7) {
      const int kc = (k0 + 1) * 64;
      const float* xs = x + (size_t)(i0 + srow) * KF + kc + ss * 8;
      float v[8];
      *(float4*)&v[0] = *(const float4*)xs;
      *(float4*)&v[4] = *(const float4*)(xs + 4);
      SPLIT8(v, aHi, aLo)
#pragma unroll
      for (int rp = 0; rp < 2; ++rp) {
        const int S = t + rp * 256, rw = S >> 3, s2 = S & 7;
        const float* wsrc = W + (size_t)(hh * 64 + rw) * KF + kc + s2 * 8;
        float wv8[8];
        *(float4*)&wv8[0] = *(const float4*)wsrc;
        *(float4*)&wv8[4] = *(const float4*)(wsrc + 4);
        SPLIT8(wv8, bHi[rp], bLo[rp])
      }
    }
#pragma unroll
    for (int kb = 0; kb < 2; ++kb) {
      const int sc = kb * 4 + lq;
      const int arow = mt * 16 + l15;
      const int offA = arow * 64 + ((sc ^ (arow & 7)) * 8);
      const short8 afh = *(const short8*)&sAh[offA];
      const short8 afl = *(const short8*)&sAl[offA];
      const int br0 = nt * 32 + l15;
      const int br1 = br0 + 16;
      const int offB0 = br0 * 64 + ((sc ^ (br0 & 7)) * 8);
      const int offB1 = br1 * 64 + ((sc ^ (br1 & 7)) * 8);
      const short8 bh0 = *(const short8*)&sBh[offB0];
      const short8 bl0 = *(const short8*)&sBl[offB0];
      const short8 bh1 = *(const short8*)&sBh[offB1];
      const short8 bl1 = *(const short8*)&sBl[offB1];
      acc[0] = __builtin_amdgcn_mfma_f32_16x16x32_bf16(afh, bh0, acc[0], 0, 0, 0);
      acc[1] = __builtin_amdgcn_mfma_f32_16x16x32_bf16(afh, bh1, acc[1], 0, 0, 0);
      acc[0] = __builtin_amdgcn_mfma_f32_16x16x32_bf16(afh, bl0, acc[0], 0, 0, 0);
      acc[1] = __builtin_amdgcn_mfma_f32_16x16x32_bf16(afh, bl1, acc[1], 0, 0, 0);
      acc[0] = __builtin_amdgcn_mfma_f32_16x16x32_bf16(afl, bh0, acc[0], 0, 0, 0);
      acc[1] = __builtin_amdgcn_mfma_f32_16x16x32_bf16(afl, bh1, acc[1], 0, 0, 0);
    }
  }

  __syncthreads();
  ushortT* ldsT = (ushortT*)smem;   // [64 d][40]
  float bias2[2], asv[2], adv[2];
#pragma unroll
  for (int bb = 0; bb < 2; ++bb) {
    const int fl = nt * 32 + bb * 16 + l15;
    bias2[bb] = Wb[hh * 64 + fl];
    asv[bb] = av[fl];
    adv[bb] = av[DD + fl];
  }
#pragma unroll
  for (int p = 0; p < 4; ++p) {
    float vs = 0.f, vd = 0.f;
#pragma unroll
    for (int bb = 0; bb < 2; ++bb) {
      const float hv = acc[bb][p] + bias2[bb];
      const ushortT hu = bfcvt(hv);
      vs = fmaf(hv, asv[bb], vs);
      vd = fmaf(hv, adv[bb], vd);
      ldsT[(nt * 32 + bb * 16 + l15) * 40 + mt * 16 + lq * 4 + p] = hu;
    }
    vs += __shfl_xor(vs, 1); vs += __shfl_xor(vs, 2);
    vs += __shfl_xor(vs, 4); vs += __shfl_xor(vs, 8);
    vd += __shfl_xor(vd, 1); vd += __shfl_xor(vd, 2);
    vd += __shfl_xor(vd, 4); vd += __shfl_xor(vd, 8);
    if (l15 == 0) {
      sredS[nt][mt * 16 + lq * 4 + p] = vs;
      sredD[nt][mt * 16 + lq * 4 + p] = vd;
    }
  }
  __syncthreads();
  if (t < 32) {
    const float s1 = sredS[0][t] + sredS[1][t];
    const float s2 = sredD[0][t] + sredD[1][t];
    const size_t gi = (size_t)hh * BN + i0 + t;
    float2 sv; sv.x = __expf(s1); sv.y = __expf(0.2f * s1);
    float2 dv; dv.x = __expf(s2); dv.y = __expf(0.2f * s2);
    *(float2*)&E12s[gi * 2] = sv;
    *(float2*)&E12d[gi * 2] = dv;
  }
  {
    const int n = t >> 6, ln = t & 63;
    const int4 v = *(const int4*)&ldsT[(n * 16 + (ln & 15)) * 40 + ((ln >> 4) * 8)];
    const size_t chunk = (((size_t)hh * 64 + blockIdx.y) * 4 + n) * 64 + ln;
    *(int4*)&hF[chunk * 8] = v;
  }
}

// ============ Kernel B v3 (best measured, R15): reg bits + cvt_pk + prefetch =
__global__ __launch_bounds__(512, 4) void k_attn(
    const ushortT* __restrict__ hF, const uint8_t* __restrict__ adjB,
    const float* __restrict__ E12s, const float* __restrict__ E12d,
    float* __restrict__ out) {
  __shared__ __align__(16) float e12[BN * 2];          // 16 KB
  __shared__ __align__(16) float cbuf[4][2 * 16 * 68]; // 34816 B
  __shared__ uint8_t abits[32 * 272];                  // 8.5 KB
  __shared__ float denP[8][2][16];

  const int t    = threadIdx.x;
  const int hh   = blockIdx.x;
  const int i0   = blockIdx.y * 32;
  const int lane = t & 63;
  const int wv   = t >> 6;
  const int l15  = lane & 15;
  const int lq   = lane >> 4;

  {
    const float4* g = (const float4*)(E12d + (size_t)hh * BN * 2);
    ((float4*)e12)[t]       = g[t];
    ((float4*)e12)[t + 512] = g[t + 512];
    const int r = t >> 4, pp = t & 15;
    *(int4*)(abits + r * 272 + pp * 16) =
        *(const int4*)(adjB + (size_t)(i0 + r) * 256 + pp * 16);
  }

  const float2 eiA = *(const float2*)&E12s[2 * ((size_t)hh * BN + i0 + l15)];
  const float2 eiB = *(const float2*)&E12s[2 * ((size_t)hh * BN + i0 + 16 + l15)];

  const short8 ones8 = {(short)0x3F80, (short)0x3F80, (short)0x3F80, (short)0x3F80,
                        (short)0x3F80, (short)0x3F80, (short)0x3F80, (short)0x3F80};

  const ushortT* hfb = hF + (size_t)hh * 131072 + (size_t)lane * 8;

  __syncthreads();   // e12 + abits staged

  const uint4 wA0 = *(const uint4*)(abits + l15 * 272 + wv * 32);
  const uint4 wA1 = *(const uint4*)(abits + l15 * 272 + wv * 32 + 16);
  const uint4 wB0 = *(const uint4*)(abits + (16 + l15) * 272 + wv * 32);
  const uint4 wB1 = *(const uint4*)(abits + (16 + l15) * 272 + wv * 32 + 16);
  const int lqs = lq * 8;

  f32x4 acc0[4] = {}, acc1[4] = {};
  f32x4 accd0 = {0.f, 0.f, 0.f, 0.f}, accd1 = {0.f, 0.f, 0.f, 0.f};

  const int jb0 = wv * 8;
  short8 bfA[4], bfB[4];
  {
    const ushortT* b0 = hfb + (size_t)(jb0 * 4) * 512;
#pragma unroll
    for (int n = 0; n < 4; ++n) bfA[n] = *(const short8*)(b0 + (size_t)n * 512);
  }

#define WSEL0(s) ((s)==0?wA0.x:(s)==1?wA0.y:(s)==2?wA0.z:(s)==3?wA0.w: \
                  (s)==4?wA1.x:(s)==5?wA1.y:(s)==6?wA1.z:wA1.w)
#define WSEL1(s) ((s)==0?wB0.x:(s)==1?wB0.y:(s)==2?wB0.z:(s)==3?wB0.w: \
                  (s)==4?wB1.x:(s)==5?wB1.y:(s)==6?wB1.z:wB1.w)

#define STEP(s, BCUR, BNXT)                                                        \
  {                                                                                \
    if ((s) < 7) {                                                                 \
      const ushortT* bn = hfb + (size_t)((jb0 + (s) + 1) * 4) * 512;               \
      _Pragma("unroll") for (int n = 0; n < 4; ++n)                                \
        BNXT[n] = *(const short8*)(bn + (size_t)n * 512);                          \
    }                                                                              \
    const int j0 = (jb0 + (s)) * 32 + lq * 8;                                      \
    const float* ep = &e12[j0 * 2];                                                \
    const float4 r0 = *(const float4*)(ep);                                        \
    const float4 r1 = *(const float4*)(ep + 4);                                    \
    const float4 r2 = *(const float4*)(ep + 8);                                    \
    const float4 r3 = *(const float4*)(ep + 12);                                   \
    const unsigned bb0 = (WSEL0(s) >> lqs) & 0xffu;                                \
    const unsigned bb1 = (WSEL1(s) >> lqs) & 0xffu;                                \
    unsigned pk0[4], pk1[4];                                                       \
    _Pragma("unroll") for (int q = 0; q < 4; ++q) {                                \
      const float4 rq = (q == 0) ? r0 : (q == 1) ? r1 : (q == 2) ? r2 : r3;        \
      float wa0 = fmaxf(eiA.x * rq.x, eiA.y * rq.y);                               \
      float wb0 = fmaxf(eiA.x * rq.z, eiA.y * rq.w);                               \
      float wa1 = fmaxf(eiB.x * rq.x, eiB.y * rq.y);                               \
      float wb1 = fmaxf(eiB.x * rq.z, eiB.y * rq.w);                               \
      wa0 = ((bb0 >> (2 * q)) & 1u) ? wa0 : 0.f;                                   \
      wb0 = ((bb0 >> (2 * q + 1)) & 1u) ? wb0 : 0.f;                               \
      wa1 = ((bb1 >> (2 * q)) & 1u) ? wa1 : 0.f;                                   \
      wb1 = ((bb1 >> (2 * q + 1)) & 1u) ? wb1 : 0.f;                               \
      asm("v_cvt_pk_bf16_f32 %0, %1, %2" : "=v"(pk0[q]) : "v"(wa0), "v"(wb0));     \
      asm("v_cvt_pk_bf16_f32 %0, %1, %2" : "=v"(pk1[q]) : "v"(wa1), "v"(wb1));     \
    }                                                                              \
    const short8 af0 = *(const short8*)pk0;                                        \
    const short8 af1 = *(const short8*)pk1;                                        \
    _Pragma("unroll") for (int n = 0; n < 4; ++n) {                                \
      acc0[n] = __builtin_amdgcn_mfma_f32_16x16x32_bf16(af0, BCUR[n], acc0[n], 0, 0, 0); \
      acc1[n] = __builtin_amdgcn_mfma_f32_16x16x32_bf16(af1, BCUR[n], acc1[n], 0, 0, 0); \
    }                                                                              \
    accd0 = __builtin_amdgcn_mfma_f32_16x16x32_bf16(af0, ones8, accd0, 0, 0, 0);   \
    accd1 = __builtin_amdgcn_mfma_f32_16x16x32_bf16(af1, ones8, accd1, 0, 0, 0);   \
  }

  STEP(0, bfA, bfB) STEP(1, bfB, bfA) STEP(2, bfA, bfB) STEP(3, bfB, bfA)
  STEP(4, bfA, bfB) STEP(5, bfB, bfA) STEP(6, bfA, bfB) STEP(7, bfB, bfA)
#undef STEP
#undef WSEL0
#undef WSEL1

  if (l15 == 0) {
#pragma unroll
    for (int p = 0; p < 4; ++p) {
      denP[wv][0][lq * 4 + p] = accd0[p];
      denP[wv][1][lq * 4 + p] = accd1[p];
    }
  }

#define CWRITE(buf)                                                     \
  _Pragma("unroll") for (int n = 0; n < 4; ++n)                         \
  _Pragma("unroll") for (int p = 0; p < 4; ++p) {                       \
    (buf)[(lq * 4 + p) * 68 + n * 16 + l15]      = acc0[n][p];          \
    (buf)[(16 + lq * 4 + p) * 68 + n * 16 + l15] = acc1[n][p];          \
  }
#define CADD(buf)                                                       \
  _Pragma("unroll") for (int n = 0; n < 4; ++n)                         \
  _Pragma("unroll") for (int p = 0; p < 4; ++p) {                       \
    acc0[n][p] += (buf)[(lq * 4 + p) * 68 + n * 16 + l15];              \
    acc1[n][p] += (buf)[(16 + lq * 4 + p) * 68 + n * 16 + l15];         \
  }

  if (wv >= 4) { CWRITE(cbuf[wv - 4]) }
  __syncthreads();
  if (wv < 4) {
    CADD(cbuf[wv])
    if (wv >= 2) { CWRITE(cbuf[wv]) }
  }
  __syncthreads();
  if (wv < 2) {
    CADD(cbuf[wv + 2])
    if (wv == 1) { CWRITE(cbuf[1]) }
  }
  __syncthreads();
  if (wv == 0) {
    CADD(cbuf[1])
    float dfin0[4], dfin1[4];
#pragma unroll
    for (int p = 0; p < 4; ++p) {
      const int row = lq * 4 + p;
      float d0 = 0.f, d1s = 0.f;
#pragma unroll
      for (int w = 0; w < 8; ++w) { d0 += denP[w][0][row]; d1s += denP[w][1][row]; }
      dfin0[p] = 1.f / d0;
      dfin1[p] = 1.f / d1s;
    }
#pragma unroll
    for (int n = 0; n < 4; ++n)
#pragma unroll
      for (int p = 0; p < 4; ++p) {
        float v0 = acc0[n][p] * dfin0[p];
        float v1 = acc1[n][p] * dfin1[p];
        v0 = v0 > 0.f ? v0 : expm1f(v0);
        v1 = v1 > 0.f ? v1 : expm1f(v1);
        out[(size_t)(i0 + lq * 4 + p) * OF + hh * 64 + n * 16 + l15] = v0;
        out[(size_t)(i0 + 16 + lq * 4 + p) * OF + hh * 64 + n * 16 + l15] = v1;
      }
  }
#undef CWRITE
#undef CADD
}

extern "C" void kernel_launch(void* const* d_in, const int* in_sizes, int n_in,
                              void* d_out, int out_size, void* d_ws, size_t ws_size,
                              hipStream_t stream) {
  const float* x  = (const float*)d_in[0];
  const int* adj  = (const int*)d_in[1];
  const float* Ww = (const float*)d_in[2];
  const float* Wb = (const float*)d_in[3];
  const float* a  = (const float*)d_in[4];
  float* outp = (float*)d_out;

  uint8_t* p = (uint8_t*)d_ws;
  ushortT* hF   = (ushortT*)(p + 0x000000);   // 2 MB, fragment-major
  float*   E12d = (float*)  (p + 0x200000);   // 128 KB
  float*   E12s = (float*)  (p + 0x220000);   // 128 KB
  uint8_t* adjB =            p + 0x240000;    // 512 KB

  k_main<<<dim3(NH, BN / 32), 256, 0, stream>>>(x, adj, Ww, Wb, a, hF, E12s, E12d, adjB);
  k_attn<<<dim3(NH, BN / 32), 512, 0, stream>>>(hF, adjB, E12s, E12d, outp);
}

// Round 20
// 32.949 us; speedup vs baseline: 3.2095x; 1.0039x over previous
//
#include <hip/hip_runtime.h>
#include <hip/hip_bf16.h>
#include <math.h>
#include <stdint.h>

#define BN 2048
#define KF 512
#define OF 512
#define NH 8
#define DD 64

typedef __attribute__((ext_vector_type(8))) short short8;
typedef __attribute__((ext_vector_type(4))) float f32x4;
typedef unsigned short ushortT;

static __device__ __forceinline__ ushortT bfcvt(float f) {
  __hip_bfloat16 h = __float2bfloat16(f);
  return *reinterpret_cast<ushortT*>(&h);
}
static __device__ __forceinline__ float bf2f(ushortT b) {
  return __uint_as_float(((unsigned)b) << 16);
}

#define SPLIT8(vsrc, dhi, dlo)                                        \
  {                                                                   \
    ushortT hi8[8], lo8[8];                                           \
    _Pragma("unroll") for (int i = 0; i < 8; ++i) {                   \
      hi8[i] = bfcvt((vsrc)[i]);                                      \
      lo8[i] = bfcvt((vsrc)[i] - bf2f(hi8[i]));                       \
    }                                                                 \
    (dhi) = *(const int4*)hi8;                                        \
    (dlo) = *(const int4*)lo8;                                        \
  }

// ============ Kernel A: adj pack + split-bf16 GEMM, fragment-major h (R13) ===
__global__ __launch_bounds__(256, 2) void k_main(
    const float* __restrict__ x, const int* __restrict__ adj,
    const float* __restrict__ W, const float* __restrict__ Wb,
    const float* __restrict__ av,
    ushortT* __restrict__ hF, float* __restrict__ E12s, float* __restrict__ E12d,
    uint8_t* __restrict__ adjB) {
  __shared__ __align__(16) uint8_t smem[24576];
  __shared__ float sredS[2][32], sredD[2][32];

  const int t    = threadIdx.x;
  const int hh   = blockIdx.x;
  const int i0   = blockIdx.y * 32;
  const int b    = hh * 64 + blockIdx.y;
  const int lane = t & 63;
  const int wv   = t >> 6;
  const int mt   = wv & 1;
  const int nt   = wv >> 1;
  const int l15  = lane & 15;
  const int lq   = lane >> 4;

  {
    const int gtid = b * 256 + t;
#pragma unroll
    for (int it = 0; it < 4; ++it) {
      const int bidx = gtid + it * (512 * 256);
      const int4 v0 = *(const int4*)(adj + (size_t)bidx * 8);
      const int4 v1 = *(const int4*)(adj + (size_t)bidx * 8 + 4);
      unsigned m = (v0.x ? 1u : 0u) | (v0.y ? 2u : 0u) | (v0.z ? 4u : 0u) | (v0.w ? 8u : 0u)
                 | (v1.x ? 16u : 0u) | (v1.y ? 32u : 0u) | (v1.z ? 64u : 0u) | (v1.w ? 128u : 0u);
      adjB[bidx] = (uint8_t)m;
    }
  }

  ushortT* sAh = (ushortT*)smem;
  ushortT* sAl = sAh + 32 * 64;
  ushortT* sBh = sAl + 32 * 64;
  ushortT* sBl = sBh + 64 * 64;

  f32x4 acc[2] = {};
  const int srow = t >> 3, ss = t & 7;
  int4 aHi, aLo, bHi[2], bLo[2];

  {
    const float* xs = x + (size_t)(i0 + srow) * KF + ss * 8;
    float v[8];
    *(float4*)&v[0] = *(const float4*)xs;
    *(float4*)&v[4] = *(const float4*)(xs + 4);
    SPLIT8(v, aHi, aLo)
#pragma unroll
    for (int rp = 0; rp < 2; ++rp) {
      const int S = t + rp * 256, rw = S >> 3, s2 = S & 7;
      const float* wsrc = W + (size_t)(hh * 64 + rw) * KF + s2 * 8;
      float wv8[8];
      *(float4*)&wv8[0] = *(const float4*)wsrc;
      *(float4*)&wv8[4] = *(const float4*)(wsrc + 4);
      SPLIT8(wv8, bHi[rp], bLo[rp])
    }
  }

  for (int k0 = 0; k0 < 8; ++k0) {
    __syncthreads();
    {
      const int offA = srow * 64 + ((ss ^ (srow & 7)) * 8);
      *(int4*)&sAh[offA] = aHi;
      *(int4*)&sAl[offA] = aLo;
#pragma unroll
      for (int rp = 0; rp < 2; ++rp) {
        const int S = t + rp * 256, rw = S >> 3, s2 = S & 7;
        const int offB = rw * 64 + ((s2 ^ (rw & 7)) * 8);
        *(int4*)&sBh[offB] = bHi[rp];
        *(int4*)&sBl[offB] = bLo[rp];
      }
    }
    __syncthreads();
    if (k0 < 7) {
      const int kc = (k0 + 1) * 64;
      const float* xs = x + (size_t)(i0 + srow) * KF + kc + ss * 8;
      float v[8];
      *(float4*)&v[0] = *(const float4*)xs;
      *(float4*)&v[4] = *(const float4*)(xs + 4);
      SPLIT8(v, aHi, aLo)
#pragma unroll
      for (int rp = 0; rp < 2; ++rp) {
        const int S = t + rp * 256, rw = S >> 3, s2 = S & 7;
        const float* wsrc = W + (size_t)(hh * 64 + rw) * KF + kc + s2 * 8;
        float wv8[8];
        *(float4*)&wv8[0] = *(const float4*)wsrc;
        *(float4*)&wv8[4] = *(const float4*)(wsrc + 4);
        SPLIT8(wv8, bHi[rp], bLo[rp])
      }
    }
#pragma unroll
    for (int kb = 0; kb < 2; ++kb) {
      const int sc = kb * 4 + lq;
      const int arow = mt * 16 + l15;
      const int offA = arow * 64 + ((sc ^ (arow & 7)) * 8);
      const short8 afh = *(const short8*)&sAh[offA];
      const short8 afl = *(const short8*)&sAl[offA];
      const int br0 = nt * 32 + l15;
      const int br1 = br0 + 16;
      const int offB0 = br0 * 64 + ((sc ^ (br0 & 7)) * 8);
      const int offB1 = br1 * 64 + ((sc ^ (br1 & 7)) * 8);
      const short8 bh0 = *(const short8*)&sBh[offB0];
      const short8 bl0 = *(const short8*)&sBl[offB0];
      const short8 bh1 = *(const short8*)&sBh[offB1];
      const short8 bl1 = *(const short8*)&sBl[offB1];
      acc[0] = __builtin_amdgcn_mfma_f32_16x16x32_bf16(afh, bh0, acc[0], 0, 0, 0);
      acc[1] = __builtin_amdgcn_mfma_f32_16x16x32_bf16(afh, bh1, acc[1], 0, 0, 0);
      acc[0] = __builtin_amdgcn_mfma_f32_16x16x32_bf16(afh, bl0, acc[0], 0, 0, 0);
      acc[1] = __builtin_amdgcn_mfma_f32_16x16x32_bf16(afh, bl1, acc[1], 0, 0, 0);
      acc[0] = __builtin_amdgcn_mfma_f32_16x16x32_bf16(afl, bh0, acc[0], 0, 0, 0);
      acc[1] = __builtin_amdgcn_mfma_f32_16x16x32_bf16(afl, bh1, acc[1], 0, 0, 0);
    }
  }

  __syncthreads();
  ushortT* ldsT = (ushortT*)smem;   // [64 d][40]
  float bias2[2], asv[2], adv[2];
#pragma unroll
  for (int bb = 0; bb < 2; ++bb) {
    const int fl = nt * 32 + bb * 16 + l15;
    bias2[bb] = Wb[hh * 64 + fl];
    asv[bb] = av[fl];
    adv[bb] = av[DD + fl];
  }
#pragma unroll
  for (int p = 0; p < 4; ++p) {
    float vs = 0.f, vd = 0.f;
#pragma unroll
    for (int bb = 0; bb < 2; ++bb) {
      const float hv = acc[bb][p] + bias2[bb];
      const ushortT hu = bfcvt(hv);
      vs = fmaf(hv, asv[bb], vs);
      vd = fmaf(hv, adv[bb], vd);
      ldsT[(nt * 32 + bb * 16 + l15) * 40 + mt * 16 + lq * 4 + p] = hu;
    }
    vs += __shfl_xor(vs, 1); vs += __shfl_xor(vs, 2);
    vs += __shfl_xor(vs, 4); vs += __shfl_xor(vs, 8);
    vd += __shfl_xor(vd, 1); vd += __shfl_xor(vd, 2);
    vd += __shfl_xor(vd, 4); vd += __shfl_xor(vd, 8);
    if (l15 == 0) {
      sredS[nt][mt * 16 + lq * 4 + p] = vs;
      sredD[nt][mt * 16 + lq * 4 + p] = vd;
    }
  }
  __syncthreads();
  if (t < 32) {
    const float s1 = sredS[0][t] + sredS[1][t];
    const float s2 = sredD[0][t] + sredD[1][t];
    const size_t gi = (size_t)hh * BN + i0 + t;
    float2 sv; sv.x = __expf(s1); sv.y = __expf(0.2f * s1);
    float2 dv; dv.x = __expf(s2); dv.y = __expf(0.2f * s2);
    *(float2*)&E12s[gi * 2] = sv;
    *(float2*)&E12d[gi * 2] = dv;
  }
  {
    const int n = t >> 6, ln = t & 63;
    const int4 v = *(const int4*)&ldsT[(n * 16 + (ln & 15)) * 40 + ((ln >> 4) * 8)];
    const size_t chunk = (((size_t)hh * 64 + blockIdx.y) * 4 + n) * 64 + ln;
    *(int4*)&hF[chunk * 8] = v;
  }
}

// ============ Kernel B v7: v3 + prefetch depth 2 (3-buffer rotation) =========
__global__ __launch_bounds__(512, 4) void k_attn(
    const ushortT* __restrict__ hF, const uint8_t* __restrict__ adjB,
    const float* __restrict__ E12s, const float* __restrict__ E12d,
    float* __restrict__ out) {
  __shared__ __align__(16) float e12[BN * 2];          // 16 KB
  __shared__ __align__(16) float cbuf[4][2 * 16 * 68]; // 34816 B
  __shared__ uint8_t abits[32 * 272];                  // 8.5 KB
  __shared__ float denP[8][2][16];

  const int t    = threadIdx.x;
  const int hh   = blockIdx.x;
  const int i0   = blockIdx.y * 32;
  const int lane = t & 63;
  const int wv   = t >> 6;
  const int l15  = lane & 15;
  const int lq   = lane >> 4;

  {
    const float4* g = (const float4*)(E12d + (size_t)hh * BN * 2);
    ((float4*)e12)[t]       = g[t];
    ((float4*)e12)[t + 512] = g[t + 512];
    const int r = t >> 4, pp = t & 15;
    *(int4*)(abits + r * 272 + pp * 16) =
        *(const int4*)(adjB + (size_t)(i0 + r) * 256 + pp * 16);
  }

  const float2 eiA = *(const float2*)&E12s[2 * ((size_t)hh * BN + i0 + l15)];
  const float2 eiB = *(const float2*)&E12s[2 * ((size_t)hh * BN + i0 + 16 + l15)];

  const short8 ones8 = {(short)0x3F80, (short)0x3F80, (short)0x3F80, (short)0x3F80,
                        (short)0x3F80, (short)0x3F80, (short)0x3F80, (short)0x3F80};

  const ushortT* hfb = hF + (size_t)hh * 131072 + (size_t)lane * 8;

  __syncthreads();   // e12 + abits staged

  const uint4 wA0 = *(const uint4*)(abits + l15 * 272 + wv * 32);
  const uint4 wA1 = *(const uint4*)(abits + l15 * 272 + wv * 32 + 16);
  const uint4 wB0 = *(const uint4*)(abits + (16 + l15) * 272 + wv * 32);
  const uint4 wB1 = *(const uint4*)(abits + (16 + l15) * 272 + wv * 32 + 16);
  const int lqs = lq * 8;

  f32x4 acc0[4] = {}, acc1[4] = {};
  f32x4 accd0 = {0.f, 0.f, 0.f, 0.f}, accd1 = {0.f, 0.f, 0.f, 0.f};

  const int jb0 = wv * 8;
  short8 bf0[4], bf1[4], bf2[4];   // 3-buffer rotation: cur = buf[s%3]
  {
    const ushortT* p0 = hfb + (size_t)(jb0 * 4) * 512;
    const ushortT* p1 = hfb + (size_t)((jb0 + 1) * 4) * 512;
#pragma unroll
    for (int n = 0; n < 4; ++n) {
      bf0[n] = *(const short8*)(p0 + (size_t)n * 512);
      bf1[n] = *(const short8*)(p1 + (size_t)n * 512);
    }
  }

#define WSEL0(s) ((s)==0?wA0.x:(s)==1?wA0.y:(s)==2?wA0.z:(s)==3?wA0.w: \
                  (s)==4?wA1.x:(s)==5?wA1.y:(s)==6?wA1.z:wA1.w)
#define WSEL1(s) ((s)==0?wB0.x:(s)==1?wB0.y:(s)==2?wB0.z:(s)==3?wB0.w: \
                  (s)==4?wB1.x:(s)==5?wB1.y:(s)==6?wB1.z:wB1.w)

#define STEP(s, BCUR, BNXT2)                                                       \
  {                                                                                \
    if ((s) < 6) {                                                                 \
      const ushortT* bn = hfb + (size_t)((jb0 + (s) + 2) * 4) * 512;               \
      _Pragma("unroll") for (int n = 0; n < 4; ++n)                                \
        BNXT2[n] = *(const short8*)(bn + (size_t)n * 512);                         \
    }                                                                              \
    const int j0 = (jb0 + (s)) * 32 + lq * 8;                                      \
    const float* ep = &e12[j0 * 2];                                                \
    const float4 r0 = *(const float4*)(ep);                                        \
    const float4 r1 = *(const float4*)(ep + 4);                                    \
    const float4 r2 = *(const float4*)(ep + 8);                                    \
    const float4 r3 = *(const float4*)(ep + 12);                                   \
    const unsigned bb0 = (WSEL0(s) >> lqs) & 0xffu;                                \
    const unsigned bb1 = (WSEL1(s) >> lqs) & 0xffu;                                \
    unsigned pk0[4], pk1[4];                                                       \
    _Pragma("unroll") for (int q = 0; q < 4; ++q) {                                \
      const float4 rq = (q == 0) ? r0 : (q == 1) ? r1 : (q == 2) ? r2 : r3;        \
      float wa0 = fmaxf(eiA.x * rq.x, eiA.y * rq.y);                               \
      float wb0 = fmaxf(eiA.x * rq.z, eiA.y * rq.w);                               \
      float wa1 = fmaxf(eiB.x * rq.x, eiB.y * rq.y);                               \
      float wb1 = fmaxf(eiB.x * rq.z, eiB.y * rq.w);                               \
      wa0 = ((bb0 >> (2 * q)) & 1u) ? wa0 : 0.f;                                   \
      wb0 = ((bb0 >> (2 * q + 1)) & 1u) ? wb0 : 0.f;                               \
      wa1 = ((bb1 >> (2 * q)) & 1u) ? wa1 : 0.f;                                   \
      wb1 = ((bb1 >> (2 * q + 1)) & 1u) ? wb1 : 0.f;                               \
      asm("v_cvt_pk_bf16_f32 %0, %1, %2" : "=v"(pk0[q]) : "v"(wa0), "v"(wb0));     \
      asm("v_cvt_pk_bf16_f32 %0, %1, %2" : "=v"(pk1[q]) : "v"(wa1), "v"(wb1));     \
    }                                                                              \
    const short8 af0 = *(const short8*)pk0;                                        \
    const short8 af1 = *(const short8*)pk1;                                        \
    _Pragma("unroll") for (int n = 0; n < 4; ++n) {                                \
      acc0[n] = __builtin_amdgcn_mfma_f32_16x16x32_bf16(af0, BCUR[n], acc0[n], 0, 0, 0); \
      acc1[n] = __builtin_amdgcn_mfma_f32_16x16x32_bf16(af1, BCUR[n], acc1[n], 0, 0, 0); \
    }                                                                              \
    accd0 = __builtin_amdgcn_mfma_f32_16x16x32_bf16(af0, ones8, accd0, 0, 0, 0);   \
    accd1 = __builtin_amdgcn_mfma_f32_16x16x32_bf16(af1, ones8, accd1, 0, 0, 0);   \
  }

  STEP(0, bf0, bf2) STEP(1, bf1, bf0) STEP(2, bf2, bf1) STEP(3, bf0, bf2)
  STEP(4, bf1, bf0) STEP(5, bf2, bf1) STEP(6, bf0, bf2) STEP(7, bf1, bf2)
#undef STEP
#undef WSEL0
#undef WSEL1

  if (l15 == 0) {
#pragma unroll
    for (int p = 0; p < 4; ++p) {
      denP[wv][0][lq * 4 + p] = accd0[p];
      denP[wv][1][lq * 4 + p] = accd1[p];
    }
  }

#define CWRITE(buf)                                                     \
  _Pragma("unroll") for (int n = 0; n < 4; ++n)                         \
  _Pragma("unroll") for (int p = 0; p < 4; ++p) {                       \
    (buf)[(lq * 4 + p) * 68 + n * 16 + l15]      = acc0[n][p];          \
    (buf)[(16 + lq * 4 + p) * 68 + n * 16 + l15] = acc1[n][p];          \
  }
#define CADD(buf)                                                       \
  _Pragma("unroll") for (int n = 0; n < 4; ++n)                         \
  _Pragma("unroll") for (int p = 0; p < 4; ++p) {                       \
    acc0[n][p] += (buf)[(lq * 4 + p) * 68 + n * 16 + l15];              \
    acc1[n][p] += (buf)[(16 + lq * 4 + p) * 68 + n * 16 + l15];         \
  }

  if (wv >= 4) { CWRITE(cbuf[wv - 4]) }
  __syncthreads();
  if (wv < 4) {
    CADD(cbuf[wv])
    if (wv >= 2) { CWRITE(cbuf[wv]) }
  }
  __syncthreads();
  if (wv < 2) {
    CADD(cbuf[wv + 2])
    if (wv == 1) { CWRITE(cbuf[1]) }
  }
  __syncthreads();
  if (wv == 0) {
    CADD(cbuf[1])
    float dfin0[4], dfin1[4];
#pragma unroll
    for (int p = 0; p < 4; ++p) {
      const int row = lq * 4 + p;
      float d0 = 0.f, d1s = 0.f;
#pragma unroll
      for (int w = 0; w < 8; ++w) { d0 += denP[w][0][row]; d1s += denP[w][1][row]; }
      dfin0[p] = 1.f / d0;
      dfin1[p] = 1.f / d1s;
    }
#pragma unroll
    for (int n = 0; n < 4; ++n)
#pragma unroll
      for (int p = 0; p < 4; ++p) {
        float v0 = acc0[n][p] * dfin0[p];
        float v1 = acc1[n][p] * dfin1[p];
        v0 = v0 > 0.f ? v0 : expm1f(v0);
        v1 = v1 > 0.f ? v1 : expm1f(v1);
        out[(size_t)(i0 + lq * 4 + p) * OF + hh * 64 + n * 16 + l15] = v0;
        out[(size_t)(i0 + 16 + lq * 4 + p) * OF + hh * 64 + n * 16 + l15] = v1;
      }
  }
#undef CWRITE
#undef CADD
}

extern "C" void kernel_launch(void* const* d_in, const int* in_sizes, int n_in,
                              void* d_out, int out_size, void* d_ws, size_t ws_size,
                              hipStream_t stream) {
  const float* x  = (const float*)d_in[0];
  const int* adj  = (const int*)d_in[1];
  const float* Ww = (const float*)d_in[2];
  const float* Wb = (const float*)d_in[3];
  const float* a  = (const float*)d_in[4];
  float* outp = (float*)d_out;

  uint8_t* p = (uint8_t*)d_ws;
  ushortT* hF   = (ushortT*)(p + 0x000000);   // 2 MB, fragment-major
  float*   E12d = (float*)  (p + 0x200000);   // 128 KB
  float*   E12s = (float*)  (p + 0x220000);   // 128 KB
  uint8_t* adjB =            p + 0x240000;    // 512 KB

  k_main<<<dim3(NH, BN / 32), 256, 0, stream>>>(x, adj, Ww, Wb, a, hF, E12s, E12d, adjB);
  k_attn<<<dim3(NH, BN / 32), 512, 0, stream>>>(hF, adjB, E12s, E12d, outp);
}